// Round 1
// 570.504 us; speedup vs baseline: 1.0332x; 1.0332x over previous
//
#include <hip/hip_runtime.h>
#include <math.h>

#define K_DIM 512
#define N_DIM 512
#define NLEAF 2048   // numpy pairwise leaves of 128 over 2^18 elements
#define BM 128
#define BN 256
#define BK 32

// ws float layout: [0]=mu, [1]=gamma, [16..16+2047]=leaf sums, [2064..4111]=leaf abs-sums
#define WS_LEAFS 16
#define WS_LEAFA (16 + NLEAF)

// ---------------------------------------------------------------------------
// NUMERICS CONTRACT (validated round 3, absmax==0.0 — DO NOT CHANGE):
//  mu/gamma: numpy fp32 pairwise tree — 2048 leaves of 128 elems, each leaf
//    via 8-accumulator pattern + combine ((r0+r1)+(r2+r3))+((r4+r5)+(r6+r7)),
//    then perfect binary tree (left+right), scale by 2^-18.
//  eff_w = fl(fl(w + fl(sign(fl(w-mu)) - w)) * gamma)
//  y: per-output single fp32 accumulator, fmaf chain, k STRICTLY ascending.
//  epilogue: yb=y+bias; cl=clip; rr=rintf(cl*7); q=rr/7; out=yb+(q-yb).
// ---------------------------------------------------------------------------

// Leaf sums: one thread per leaf, sequential 8-acc pattern (bit-exact order).
__global__ void leaf_kernel(const float* __restrict__ w, float* __restrict__ ws) {
  const int leaf = blockIdx.x * blockDim.x + threadIdx.x;  // 2048 total
  const float* p = w + leaf * 128;
  float rs[8], ra[8];
  #pragma unroll
  for (int j = 0; j < 8; ++j) { const float v = p[j]; rs[j] = v; ra[j] = fabsf(v); }
  for (int i = 8; i < 128; i += 8) {
    #pragma unroll
    for (int j = 0; j < 8; ++j) { const float v = p[i + j]; rs[j] += v; ra[j] += fabsf(v); }
  }
  ws[WS_LEAFS + leaf] = ((rs[0] + rs[1]) + (rs[2] + rs[3])) + ((rs[4] + rs[5]) + (rs[6] + rs[7]));
  ws[WS_LEAFA + leaf] = ((ra[0] + ra[1]) + (ra[2] + ra[3])) + ((ra[4] + ra[5]) + (ra[6] + ra[7]));
}

// Binary-tree combine of the 2048 leaf partials, exact numpy pairing.
__global__ void tree_kernel(float* __restrict__ ws) {
  __shared__ float bufS[4096];
  __shared__ float bufA[4096];
  const int t = threadIdx.x;  // 256 threads, 1 block
  for (int i = t; i < NLEAF; i += 256) {
    bufS[i] = ws[WS_LEAFS + i];
    bufA[i] = ws[WS_LEAFA + i];
  }
  __syncthreads();
  int src = 0, n = NLEAF;
  while (n > 1) {
    const int dst = src + n;
    n >>= 1;
    for (int i = t; i < n; i += 256) {
      bufS[dst + i] = bufS[src + 2 * i] + bufS[src + 2 * i + 1];
      bufA[dst + i] = bufA[src + 2 * i] + bufA[src + 2 * i + 1];
    }
    __syncthreads();
    src = dst;
  }
  if (t == 0) {
    ws[0] = bufS[src] * (1.0f / 262144.0f);  // exact pow2 scale == np divide
    ws[1] = bufA[src] * (1.0f / 262144.0f);
  }
}

// 128x256 block tile, 256 threads, 8x16 micro-tile:
//   rows = h*64 + tm*4 + i  (h=0..1, tm = t>>4, i=0..3)
//   cols = g*64 + tn*4 + j  (g=0..3, tn = t&15, j=0..3)
// Per kg (4 k): 8 A ds_read_b128 + 16 B ds_read_b128 for 512 FMAs
// (F/R = 21.3 vs 16 before -> LDS-issue ceiling 89% instead of 66%).
// A reads: 1 unique addr per quarter-wave phase (broadcast, conflict-free).
// B reads: 16 unique addrs spanning 64 consecutive dwords (2 req/bank, free).
__global__ __launch_bounds__(256, 2) void gemm_kernel(
    const float* __restrict__ x, const float* __restrict__ w,
    const float* __restrict__ bias, const float* __restrict__ ws,
    float* __restrict__ out) {
  __shared__ float As[BM][BK + 4];  // [m][k], 128 x 36 dwords (16B-aligned rows)
  __shared__ float Bs[BK][BN + 4];  // [k][n], 32 x 260 dwords

  const float mu = ws[0];
  const float gamma = ws[1];
  const int t = threadIdx.x;
  const int tn = t & 15;   // col group
  const int tm = t >> 4;   // row group (0..15)
  const int rowBase = blockIdx.x * BM;
  const int colBase = blockIdx.y * BN;

  float acc[2][4][4][4];
  #pragma unroll
  for (int h = 0; h < 2; ++h)
    #pragma unroll
    for (int g = 0; g < 4; ++g)
      #pragma unroll
      for (int i = 0; i < 4; ++i)
        #pragma unroll
        for (int j = 0; j < 4; ++j) acc[h][g][i][j] = 0.0f;

  for (int kc = 0; kc < K_DIM; kc += BK) {  // 16 chunks, ascending k
    // stage A: 128 rows x 32 k, coalesced (8 lanes * 16B = 128B per row)
    #pragma unroll
    for (int p = 0; p < 4; ++p) {
      const int r = (t >> 3) + 32 * p;
      const int k4 = (t & 7) * 4;
      const float4 v = *(const float4*)&x[(size_t)(rowBase + r) * K_DIM + kc + k4];
      *(float4*)&As[r][k4] = v;
    }
    // stage B: 32 k x 256 n, fused faithful-fp32 STE weight DAG
    #pragma unroll
    for (int p = 0; p < 8; ++p) {
      const int kk = (t >> 6) + 4 * p;
      const int n4 = (t & 63) * 4;
      const float4 v = *(const float4*)&w[(size_t)(kc + kk) * N_DIM + colBase + n4];
      float4 e;
      const float* vi = &v.x;
      float* ei = &e.x;
      #pragma unroll
      for (int c = 0; c < 4; ++c) {
        const float wv = vi[c];
        const float wc = wv - mu;
        const float bin = (wc > 0.0f) ? 1.0f : ((wc < 0.0f) ? -1.0f : 0.0f);
        const float ste = wv + (bin - wv);   // keep exact fp32 DAG
        ei[c] = ste * gamma;
      }
      *(float4*)&Bs[kk][n4] = e;
    }
    __syncthreads();

    #pragma unroll
    for (int kg = 0; kg < 8; ++kg) {  // 8 groups of 4 k
      float4 a[2][4];
      #pragma unroll
      for (int h = 0; h < 2; ++h)
        #pragma unroll
        for (int i = 0; i < 4; ++i)
          a[h][i] = *(const float4*)&As[h * 64 + tm * 4 + i][kg * 4];
      #pragma unroll
      for (int kk = 0; kk < 4; ++kk) {  // k ascending within group
        float4 b[4];
        #pragma unroll
        for (int g = 0; g < 4; ++g)
          b[g] = *(const float4*)&Bs[kg * 4 + kk][g * 64 + tn * 4];
        #pragma unroll
        for (int h = 0; h < 2; ++h)
          #pragma unroll
          for (int i = 0; i < 4; ++i) {
            const float av = (&a[h][i].x)[kk];
            #pragma unroll
            for (int g = 0; g < 4; ++g) {
              const float* bp = &b[g].x;
              #pragma unroll
              for (int j = 0; j < 4; ++j)
                acc[h][g][i][j] = fmaf(av, bp[j], acc[h][g][i][j]);
            }
          }
      }
    }
    __syncthreads();
  }

  // faithful fp32 epilogue (unchanged DAG from validated round 3)
  #pragma unroll
  for (int h = 0; h < 2; ++h)
    #pragma unroll
    for (int i = 0; i < 4; ++i) {
      const size_t row = (size_t)(rowBase + h * 64 + tm * 4 + i);
      #pragma unroll
      for (int g = 0; g < 4; ++g) {
        const int col = colBase + g * 64 + tn * 4;
        float4 o;
        float* op = &o.x;
        #pragma unroll
        for (int j = 0; j < 4; ++j) {
          const float yb = acc[h][g][i][j] + bias[col + j];
          const float cl = fminf(fmaxf(yb, -1.0f), 1.0f);
          const float t7 = cl * 7.0f;
          const float rr = rintf(t7);
          const float q = rr / 7.0f;
          op[j] = yb + (q - yb);
        }
        *(float4*)&out[row * N_DIM + col] = o;
      }
    }
}

extern "C" void kernel_launch(void* const* d_in, const int* in_sizes, int n_in,
                              void* d_out, int out_size, void* d_ws, size_t ws_size,
                              hipStream_t stream) {
  const float* x = (const float*)d_in[0];
  const float* w = (const float*)d_in[1];
  const float* bias = (const float*)d_in[2];
  float* out = (float*)d_out;
  float* ws = (float*)d_ws;  // uses 16448 bytes

  const int M = in_sizes[0] / K_DIM;  // 65536 rows

  leaf_kernel<<<NLEAF / 256, 256, 0, stream>>>(w, ws);
  tree_kernel<<<1, 256, 0, stream>>>(ws);
  gemm_kernel<<<dim3(M / BM, N_DIM / BN), 256, 0, stream>>>(x, w, bias, ws, out);
}